// Round 2
// baseline (1726.639 us; speedup 1.0000x reference)
//
#include <hip/hip_runtime.h>
#include <math.h>

#define SEQ   1024
#define BATCH 1024
#define IN_F  57
#define H_F   128
#define OUT_F 18

typedef float f16v __attribute__((ext_vector_type(16)));
typedef float f8v  __attribute__((ext_vector_type(8)));

// Block: 256 threads (4 waves) = 2 batch rows × 128 output neurons, persistent
// over all 1024 steps. j = tid&127, bp = tid>>7 (wave-uniform -> LDS h reads
// are pure broadcast). Weights live in explicit ext_vector register variables
// (NOT arrays -> no alloca -> no scratch spill; R1 showed promote-alloca
// failure at VGPR_Count=128). h double-buffered in LDS, one barrier/step.
__global__ __launch_bounds__(256, 2) void rnn_persistent_kernel(
    const float* __restrict__ X,     // [SEQ][BATCH][IN_F]
    const float* __restrict__ W_ih,  // [H_F][IN_F]
    const float* __restrict__ b_ih,  // [H_F]
    const float* __restrict__ W_hh,  // [H_F][H_F]
    const float* __restrict__ b_hh,  // [H_F]
    const float* __restrict__ W_ho,  // [OUT_F][H_F]
    const float* __restrict__ b_ho,  // [OUT_F]
    float* __restrict__ out)         // [BATCH][OUT_F] ++ [BATCH][H_F]
{
    const int tid = threadIdx.x;
    const int j  = tid & (H_F - 1);
    const int bp = tid >> 7;             // 0 or 1 (wave-uniform)
    const int b0 = blockIdx.x * 2;

    __shared__ float h_lds[2][2][H_F];       // [buf][bp][k]
    __shared__ float x_lds[2][2][60];        // [buf][bp][i] (57 padded to 60)
    __shared__ float logits_lds[2][OUT_F];
    __shared__ float red_lds[2][2];

    // ---- W_hh row j -> 8 x f32x16 register vectors (rows are 512B-aligned) ----
    const float* wr = W_hh + j * H_F;
    f16v wh0 = *(const f16v*)(wr +   0);
    f16v wh1 = *(const f16v*)(wr +  16);
    f16v wh2 = *(const f16v*)(wr +  32);
    f16v wh3 = *(const f16v*)(wr +  48);
    f16v wh4 = *(const f16v*)(wr +  64);
    f16v wh5 = *(const f16v*)(wr +  80);
    f16v wh6 = *(const f16v*)(wr +  96);
    f16v wh7 = *(const f16v*)(wr + 112);

    // ---- W_ih row j (57 floats, only 4B-aligned) -> element-wise insert ----
    const float* wr2 = W_ih + j * IN_F;
    f16v wi0, wi1, wi2;
    f8v  wi3;
    #pragma unroll
    for (int i = 0; i < 16; ++i) {
        wi0[i] = wr2[i];
        wi1[i] = wr2[16 + i];
        wi2[i] = wr2[32 + i];
    }
    #pragma unroll
    for (int i = 0; i < 8; ++i) wi3[i] = wr2[48 + i];
    const float w56  = wr2[56];
    const float bias = b_ih[j] + b_hh[j];

    // ---- init h0 = 0, stage x_0 ----
    h_lds[0][bp][j] = 0.0f;
    if (tid < 2 * IN_F) {
        int r = (tid >= IN_F) ? 1 : 0;
        int c = tid - r * IN_F;
        x_lds[0][r][c] = X[(size_t)b0 * IN_F + tid];
    }
    __syncthreads();

    const size_t stepstride = (size_t)BATCH * IN_F;
    const int pre_r = (tid >= IN_F) ? 1 : 0;
    const int pre_c = tid - pre_r * IN_F;
    const bool is_pre = (tid < 2 * IN_F);

#define MACH(W, P, off) do {                                       \
        float4 p0 = *(const float4*)((P) + (off));                 \
        float4 p1 = *(const float4*)((P) + (off) + 4);             \
        float4 p2 = *(const float4*)((P) + (off) + 8);             \
        float4 p3 = *(const float4*)((P) + (off) + 12);            \
        a0 = fmaf(W[0],  p0.x, a0); a1 = fmaf(W[1],  p0.y, a1);    \
        a2 = fmaf(W[2],  p0.z, a2); a3 = fmaf(W[3],  p0.w, a3);    \
        a0 = fmaf(W[4],  p1.x, a0); a1 = fmaf(W[5],  p1.y, a1);    \
        a2 = fmaf(W[6],  p1.z, a2); a3 = fmaf(W[7],  p1.w, a3);    \
        a0 = fmaf(W[8],  p2.x, a0); a1 = fmaf(W[9],  p2.y, a1);    \
        a2 = fmaf(W[10], p2.z, a2); a3 = fmaf(W[11], p2.w, a3);    \
        a0 = fmaf(W[12], p3.x, a0); a1 = fmaf(W[13], p3.y, a1);    \
        a2 = fmaf(W[14], p3.z, a2); a3 = fmaf(W[15], p3.w, a3);    \
    } while (0)

#define STEP(CB, NB, T) do {                                                   \
        float xpre = 0.0f;                                                     \
        const bool do_pre = ((T) + 1 < SEQ) && is_pre;                         \
        if (do_pre)                                                            \
            xpre = X[(size_t)((T) + 1) * stepstride + (size_t)b0 * IN_F + tid];\
        float a0 = bias, a1 = 0.0f, a2 = 0.0f, a3 = 0.0f;                      \
        const float* hb = &h_lds[CB][bp][0];                                   \
        MACH(wh0, hb,   0); MACH(wh1, hb,  16);                                \
        MACH(wh2, hb,  32); MACH(wh3, hb,  48);                                \
        MACH(wh4, hb,  64); MACH(wh5, hb,  80);                                \
        MACH(wh6, hb,  96); MACH(wh7, hb, 112);                                \
        const float* xb = &x_lds[CB][bp][0];                                   \
        MACH(wi0, xb, 0); MACH(wi1, xb, 16); MACH(wi2, xb, 32);                \
        {                                                                      \
            float4 q0 = *(const float4*)(xb + 48);                             \
            float4 q1 = *(const float4*)(xb + 52);                             \
            a0 = fmaf(wi3[0], q0.x, a0); a1 = fmaf(wi3[1], q0.y, a1);          \
            a2 = fmaf(wi3[2], q0.z, a2); a3 = fmaf(wi3[3], q0.w, a3);          \
            a0 = fmaf(wi3[4], q1.x, a0); a1 = fmaf(wi3[5], q1.y, a1);          \
            a2 = fmaf(wi3[6], q1.z, a2); a3 = fmaf(wi3[7], q1.w, a3);          \
        }                                                                      \
        a0 = fmaf(w56, xb[56], a0);                                            \
        float z = (a0 + a1) + (a2 + a3);                                       \
        z = fminf(fmaxf(z, -10.0f), 10.0f);                                    \
        float e = __expf(2.0f * z);                                            \
        float hnew = (e - 1.0f) / (e + 1.0f);                                  \
        h_lds[NB][bp][j] = hnew;                                               \
        if (do_pre) x_lds[NB][pre_r][pre_c] = xpre;                            \
        __syncthreads();                                                       \
    } while (0)

    for (int t = 0; t < SEQ; t += 2) {
        STEP(0, 1, t);
        STEP(1, 0, t + 1);
    }
#undef STEP
#undef MACH

    // SEQ even -> final h in buffer 0
    float* hT = out + (size_t)BATCH * OUT_F;
    hT[(size_t)(b0 + bp) * H_F + j] = h_lds[0][bp][j];

    // ---- logits [2][18] on threads 0..35 ----
    if (tid < 2 * OUT_F) {
        int bb = tid / OUT_F;
        int o  = tid - bb * OUT_F;
        float acc = b_ho[o];
        #pragma unroll
        for (int k = 0; k < H_F; ++k)
            acc = fmaf(h_lds[0][bb][k], W_ho[o * H_F + k], acc);
        logits_lds[bb][o] = acc;
    }
    __syncthreads();

    if (tid < 2) {
        float m = -INFINITY;
        #pragma unroll
        for (int o = 0; o < OUT_F; ++o) m = fmaxf(m, logits_lds[tid][o]);
        float s = 0.0f;
        #pragma unroll
        for (int o = 0; o < OUT_F; ++o) s += expf(logits_lds[tid][o] - m);
        red_lds[tid][0] = m;
        red_lds[tid][1] = logf(s);
    }
    __syncthreads();

    if (tid < 2 * OUT_F) {
        int bb = tid / OUT_F;
        int o  = tid - bb * OUT_F;
        out[(size_t)(b0 + bb) * OUT_F + o] =
            logits_lds[bb][o] - red_lds[bb][0] - red_lds[bb][1];
    }
}

extern "C" void kernel_launch(void* const* d_in, const int* in_sizes, int n_in,
                              void* d_out, int out_size, void* d_ws, size_t ws_size,
                              hipStream_t stream) {
    const float* X    = (const float*)d_in[0];
    const float* W_ih = (const float*)d_in[1];
    const float* b_ih = (const float*)d_in[2];
    const float* W_hh = (const float*)d_in[3];
    const float* b_hh = (const float*)d_in[4];
    const float* W_ho = (const float*)d_in[5];
    const float* b_ho = (const float*)d_in[6];
    float* out = (float*)d_out;

    rnn_persistent_kernel<<<dim3(BATCH / 2), dim3(256), 0, stream>>>(
        X, W_ih, b_ih, W_hh, b_hh, W_ho, b_ho, out);
}

// Round 3
// 1722.486 us; speedup vs baseline: 1.0024x; 1.0024x over previous
//
#include <hip/hip_runtime.h>
#include <math.h>

#define SEQ   1024
#define BATCH 1024
#define IN_F  57
#define H_F   128
#define OUT_F 18

typedef float f16v __attribute__((ext_vector_type(16)));
typedef float f8v  __attribute__((ext_vector_type(8)));

// Block: 256 threads (4 waves) = 2 batch rows x 128 neurons, persistent over
// all 1024 steps. j = tid&127, bp = tid>>7 (wave-uniform -> LDS h reads are
// pure broadcast). Weights in ext_vector register values.
//
// amdgpu_waves_per_eu(2,2): R2 showed VGPR_Count=124 (just under the 128 cap
// for the scheduler's default 4-waves/EU target) -> compiler rematerialized
// weight loads from global inside the K-loop (VALUBusy 34%, vmcnt-bound).
// Pinning max waves/EU to 2 raises the allocator budget to 256 VGPRs so the
// ~185 weight floats stay register-resident.
__global__ __launch_bounds__(256)
__attribute__((amdgpu_waves_per_eu(2, 2)))
void rnn_persistent_kernel(
    const float* __restrict__ X,     // [SEQ][BATCH][IN_F]
    const float* __restrict__ W_ih,  // [H_F][IN_F]
    const float* __restrict__ b_ih,  // [H_F]
    const float* __restrict__ W_hh,  // [H_F][H_F]
    const float* __restrict__ b_hh,  // [H_F]
    const float* __restrict__ W_ho,  // [OUT_F][H_F]
    const float* __restrict__ b_ho,  // [OUT_F]
    float* __restrict__ out)         // [BATCH][OUT_F] ++ [BATCH][H_F]
{
    const int tid = threadIdx.x;
    const int j  = tid & (H_F - 1);
    const int bp = tid >> 7;             // 0 or 1 (wave-uniform)
    const int b0 = blockIdx.x * 2;

    __shared__ float h_lds[2][2][H_F];       // [buf][bp][k]
    __shared__ float x_lds[2][2][60];        // [buf][bp][i] (57 padded to 60)
    __shared__ float logits_lds[2][OUT_F];
    __shared__ float red_lds[2][2];

    // ---- W_hh row j -> 8 x f32x16 register vectors (rows 512B-aligned) ----
    const float* wr = W_hh + j * H_F;
    f16v wh0 = *(const f16v*)(wr +   0);
    f16v wh1 = *(const f16v*)(wr +  16);
    f16v wh2 = *(const f16v*)(wr +  32);
    f16v wh3 = *(const f16v*)(wr +  48);
    f16v wh4 = *(const f16v*)(wr +  64);
    f16v wh5 = *(const f16v*)(wr +  80);
    f16v wh6 = *(const f16v*)(wr +  96);
    f16v wh7 = *(const f16v*)(wr + 112);

    // ---- W_ih row j (57 floats, 4B-aligned) ----
    const float* wr2 = W_ih + j * IN_F;
    f16v wi0, wi1, wi2;
    f8v  wi3;
    #pragma unroll
    for (int i = 0; i < 16; ++i) {
        wi0[i] = wr2[i];
        wi1[i] = wr2[16 + i];
        wi2[i] = wr2[32 + i];
    }
    #pragma unroll
    for (int i = 0; i < 8; ++i) wi3[i] = wr2[48 + i];
    const float w56  = wr2[56];
    const float bias = b_ih[j] + b_hh[j];

    // ---- init h0 = 0, stage x_0 ----
    h_lds[0][bp][j] = 0.0f;
    if (tid < 2 * IN_F) {
        int r = (tid >= IN_F) ? 1 : 0;
        int c = tid - r * IN_F;
        x_lds[0][r][c] = X[(size_t)b0 * IN_F + tid];
    }
    __syncthreads();

    const size_t stepstride = (size_t)BATCH * IN_F;
    const int pre_r = (tid >= IN_F) ? 1 : 0;
    const int pre_c = tid - pre_r * IN_F;
    const bool is_pre = (tid < 2 * IN_F);

#define MACH(W, P, off) do {                                       \
        float4 p0 = *(const float4*)((P) + (off));                 \
        float4 p1 = *(const float4*)((P) + (off) + 4);             \
        float4 p2 = *(const float4*)((P) + (off) + 8);             \
        float4 p3 = *(const float4*)((P) + (off) + 12);            \
        a0 = fmaf(W[0],  p0.x, a0); a1 = fmaf(W[1],  p0.y, a1);    \
        a2 = fmaf(W[2],  p0.z, a2); a3 = fmaf(W[3],  p0.w, a3);    \
        a0 = fmaf(W[4],  p1.x, a0); a1 = fmaf(W[5],  p1.y, a1);    \
        a2 = fmaf(W[6],  p1.z, a2); a3 = fmaf(W[7],  p1.w, a3);    \
        a0 = fmaf(W[8],  p2.x, a0); a1 = fmaf(W[9],  p2.y, a1);    \
        a2 = fmaf(W[10], p2.z, a2); a3 = fmaf(W[11], p2.w, a3);    \
        a0 = fmaf(W[12], p3.x, a0); a1 = fmaf(W[13], p3.y, a1);    \
        a2 = fmaf(W[14], p3.z, a2); a3 = fmaf(W[15], p3.w, a3);    \
    } while (0)

#define STEP(CB, NB, T) do {                                                   \
        float xpre = 0.0f;                                                     \
        const bool do_pre = ((T) + 1 < SEQ) && is_pre;                         \
        if (do_pre)                                                            \
            xpre = X[(size_t)((T) + 1) * stepstride + (size_t)b0 * IN_F + tid];\
        float a0 = bias, a1 = 0.0f, a2 = 0.0f, a3 = 0.0f;                      \
        const float* hb = &h_lds[CB][bp][0];                                   \
        MACH(wh0, hb,   0); MACH(wh1, hb,  16);                                \
        MACH(wh2, hb,  32); MACH(wh3, hb,  48);                                \
        MACH(wh4, hb,  64); MACH(wh5, hb,  80);                                \
        MACH(wh6, hb,  96); MACH(wh7, hb, 112);                                \
        const float* xb = &x_lds[CB][bp][0];                                   \
        MACH(wi0, xb, 0); MACH(wi1, xb, 16); MACH(wi2, xb, 32);                \
        {                                                                      \
            float4 q0 = *(const float4*)(xb + 48);                             \
            float4 q1 = *(const float4*)(xb + 52);                             \
            a0 = fmaf(wi3[0], q0.x, a0); a1 = fmaf(wi3[1], q0.y, a1);          \
            a2 = fmaf(wi3[2], q0.z, a2); a3 = fmaf(wi3[3], q0.w, a3);          \
            a0 = fmaf(wi3[4], q1.x, a0); a1 = fmaf(wi3[5], q1.y, a1);          \
            a2 = fmaf(wi3[6], q1.z, a2); a3 = fmaf(wi3[7], q1.w, a3);          \
        }                                                                      \
        a0 = fmaf(w56, xb[56], a0);                                            \
        float z = (a0 + a1) + (a2 + a3);                                       \
        z = fminf(fmaxf(z, -10.0f), 10.0f);                                    \
        float e = __expf(2.0f * z);                                            \
        float hnew = (e - 1.0f) * __builtin_amdgcn_rcpf(e + 1.0f);             \
        h_lds[NB][bp][j] = hnew;                                               \
        if (do_pre) x_lds[NB][pre_r][pre_c] = xpre;                            \
        __syncthreads();                                                       \
    } while (0)

    for (int t = 0; t < SEQ; t += 2) {
        STEP(0, 1, t);
        STEP(1, 0, t + 1);
    }
#undef STEP
#undef MACH

    // SEQ even -> final h in buffer 0
    float* hT = out + (size_t)BATCH * OUT_F;
    hT[(size_t)(b0 + bp) * H_F + j] = h_lds[0][bp][j];

    // ---- logits [2][18] on threads 0..35 ----
    if (tid < 2 * OUT_F) {
        int bb = tid / OUT_F;
        int o  = tid - bb * OUT_F;
        float acc = b_ho[o];
        #pragma unroll
        for (int k = 0; k < H_F; ++k)
            acc = fmaf(h_lds[0][bb][k], W_ho[o * H_F + k], acc);
        logits_lds[bb][o] = acc;
    }
    __syncthreads();

    if (tid < 2) {
        float m = -INFINITY;
        #pragma unroll
        for (int o = 0; o < OUT_F; ++o) m = fmaxf(m, logits_lds[tid][o]);
        float s = 0.0f;
        #pragma unroll
        for (int o = 0; o < OUT_F; ++o) s += expf(logits_lds[tid][o] - m);
        red_lds[tid][0] = m;
        red_lds[tid][1] = logf(s);
    }
    __syncthreads();

    if (tid < 2 * OUT_F) {
        int bb = tid / OUT_F;
        int o  = tid - bb * OUT_F;
        out[(size_t)(b0 + bb) * OUT_F + o] =
            logits_lds[bb][o] - red_lds[bb][0] - red_lds[bb][1];
    }
}

extern "C" void kernel_launch(void* const* d_in, const int* in_sizes, int n_in,
                              void* d_out, int out_size, void* d_ws, size_t ws_size,
                              hipStream_t stream) {
    const float* X    = (const float*)d_in[0];
    const float* W_ih = (const float*)d_in[1];
    const float* b_ih = (const float*)d_in[2];
    const float* W_hh = (const float*)d_in[3];
    const float* b_hh = (const float*)d_in[4];
    const float* W_ho = (const float*)d_in[5];
    const float* b_ho = (const float*)d_in[6];
    float* out = (float*)d_out;

    rnn_persistent_kernel<<<dim3(BATCH / 2), dim3(256), 0, stream>>>(
        X, W_ih, b_ih, W_hh, b_hh, W_ho, b_ho, out);
}

// Round 4
// 891.058 us; speedup vs baseline: 1.9377x; 1.9331x over previous
//
#include <hip/hip_runtime.h>
#include <math.h>

#define SEQ   1024
#define BATCH 1024
#define IN_F  57
#define H_F   128
#define OUT_F 18
#define MROWS 16     // batch rows per block
#define HSTR  136    // h_lds row stride in bf16: 272 B = 16B-aligned, banks spread (68 dw/row)
#define XSTR  72     // x_lds row stride in bf16: 144 B

typedef __attribute__((ext_vector_type(8))) short bf8;     // 8 bf16 (4 VGPRs) MFMA A/B frag
typedef __attribute__((ext_vector_type(4))) float f32x4;   // MFMA C/D frag

static __device__ __forceinline__ short f2bf(float f) {    // fp32 -> bf16 RNE
    unsigned u = __builtin_bit_cast(unsigned, f);
    u = (u + 0x7FFFu + ((u >> 16) & 1u)) >> 16;
    return (short)u;
}
static __device__ __forceinline__ float bf2f(short s) {
    unsigned u = ((unsigned)(unsigned short)s) << 16;
    return __builtin_bit_cast(float, u);
}

// 64 blocks x 256 threads. Block owns 16 batch rows for the whole sequence.
// Wave wv owns output columns [32*wv, 32*wv+32) as two 16x16 MFMA tiles.
// W_hh row j is the B-fragment source (W is [N][K] row-major = B^T form).
// h round-trips LDS in bf16 (C-layout write -> A-layout read), 1 barrier/step.
__global__ __launch_bounds__(256) void rnn_mfma_kernel(
    const float* __restrict__ X,     // [SEQ][BATCH][IN_F]
    const float* __restrict__ W_ih,  // [H_F][IN_F]
    const float* __restrict__ b_ih,  // [H_F]
    const float* __restrict__ W_hh,  // [H_F][H_F]
    const float* __restrict__ b_hh,  // [H_F]
    const float* __restrict__ W_ho,  // [OUT_F][H_F]
    const float* __restrict__ b_ho,  // [OUT_F]
    float* __restrict__ out)         // [BATCH][OUT_F] ++ [BATCH][H_F]
{
    const int tid  = threadIdx.x;
    const int lane = tid & 63;
    const int wv   = tid >> 6;       // wave 0..3
    const int n16  = lane & 15;      // n within tile (B/D) and m within tile (A)
    const int quad = lane >> 4;      // 0..3
    const int b0   = blockIdx.x * MROWS;

    __shared__ short h_lds[2][MROWS][HSTR];
    __shared__ short x_lds[2][MROWS][XSTR];
    __shared__ float logits_lds[MROWS][OUT_F];
    __shared__ float red_lds[MROWS][2];

    const int j0 = wv * 32 + n16;    // tile-0 output column
    const int j1 = j0 + 16;          // tile-1 output column

    // ---- W_hh B-frags -> registers (bf16), 8 frags ----
    const float* wp0 = W_hh + j0 * H_F + quad * 8;
    const float* wp1 = W_hh + j1 * H_F + quad * 8;
#define LDW8(P) ({ \
        f32x4 p_ = *(const f32x4*)(P); \
        f32x4 q_ = *(const f32x4*)((P) + 4); \
        bf8 f_; \
        f_[0]=f2bf(p_[0]); f_[1]=f2bf(p_[1]); f_[2]=f2bf(p_[2]); f_[3]=f2bf(p_[3]); \
        f_[4]=f2bf(q_[0]); f_[5]=f2bf(q_[1]); f_[6]=f2bf(q_[2]); f_[7]=f2bf(q_[3]); \
        f_; })
    bf8 wh00 = LDW8(wp0 +  0), wh01 = LDW8(wp0 + 32), wh02 = LDW8(wp0 + 64), wh03 = LDW8(wp0 + 96);
    bf8 wh10 = LDW8(wp1 +  0), wh11 = LDW8(wp1 + 32), wh12 = LDW8(wp1 + 64), wh13 = LDW8(wp1 + 96);

    // ---- W_ih B-frags (K padded 57->64 with zeros), 4 frags ----
#define LDWI(J, KS) ({ \
        bf8 f_; \
        _Pragma("unroll") \
        for (int i_ = 0; i_ < 8; ++i_) { \
            int k_ = (KS) * 32 + quad * 8 + i_; \
            f_[i_] = (k_ < IN_F) ? f2bf(W_ih[(J) * IN_F + k_]) : (short)0; \
        } f_; })
    bf8 wi00 = LDWI(j0, 0), wi01 = LDWI(j0, 1), wi10 = LDWI(j1, 0), wi11 = LDWI(j1, 1);

    const float bias0 = b_ih[j0] + b_hh[j0];
    const float bias1 = b_ih[j1] + b_hh[j1];

    // ---- init: h0 = 0 (buf0), zero x pads, stage x_0 ----
    for (int i = tid; i < MROWS * HSTR; i += 256) (&h_lds[0][0][0])[i] = 0;
    for (int i = tid; i < 2 * MROWS * XSTR; i += 256) (&x_lds[0][0][0])[i] = 0;
    if (tid < 228) {  // 16 rows x 57 = 912 floats = 228 float4 (16B-aligned)
        f32x4 v = *(const f32x4*)(X + (size_t)b0 * IN_F + tid * 4);
        #pragma unroll
        for (int e = 0; e < 4; ++e) {
            int idx = tid * 4 + e;
            int m = (int)((unsigned)idx / 57u);
            int k = idx - m * 57;
            x_lds[0][m][k] = f2bf(v[e]);
        }
    }
    __syncthreads();

    const size_t tstride = (size_t)BATCH * IN_F;

#define MFMA __builtin_amdgcn_mfma_f32_16x16x32_bf16
#define STEP(CB, NB, T) do { \
        f32x4 xp = {0.f, 0.f, 0.f, 0.f}; \
        const bool pre = ((T) + 1 < SEQ) && (tid < 228); \
        if (pre) xp = *(const f32x4*)(X + (size_t)((T) + 1) * tstride + (size_t)b0 * IN_F + tid * 4); \
        const short* hc = &h_lds[CB][0][0] + n16 * HSTR + quad * 8; \
        const short* xc = &x_lds[CB][0][0] + n16 * XSTR + quad * 8; \
        bf8 ah0 = *(const bf8*)(hc +  0); \
        bf8 ah1 = *(const bf8*)(hc + 32); \
        bf8 ah2 = *(const bf8*)(hc + 64); \
        bf8 ah3 = *(const bf8*)(hc + 96); \
        bf8 ax0 = *(const bf8*)(xc +  0); \
        bf8 ax1 = *(const bf8*)(xc + 32); \
        f32x4 c0 = {bias0, bias0, bias0, bias0}; \
        f32x4 c1 = {bias1, bias1, bias1, bias1}; \
        c0 = MFMA(ah0, wh00, c0, 0, 0, 0); \
        c1 = MFMA(ah0, wh10, c1, 0, 0, 0); \
        c0 = MFMA(ah1, wh01, c0, 0, 0, 0); \
        c1 = MFMA(ah1, wh11, c1, 0, 0, 0); \
        c0 = MFMA(ah2, wh02, c0, 0, 0, 0); \
        c1 = MFMA(ah2, wh12, c1, 0, 0, 0); \
        c0 = MFMA(ah3, wh03, c0, 0, 0, 0); \
        c1 = MFMA(ah3, wh13, c1, 0, 0, 0); \
        c0 = MFMA(ax0, wi00, c0, 0, 0, 0); \
        c1 = MFMA(ax0, wi10, c1, 0, 0, 0); \
        c0 = MFMA(ax1, wi01, c0, 0, 0, 0); \
        c1 = MFMA(ax1, wi11, c1, 0, 0, 0); \
        short* hn = &h_lds[NB][0][0]; \
        _Pragma("unroll") \
        for (int r = 0; r < 4; ++r) { \
            int m = quad * 4 + r;  /* D row = batch row */ \
            float z0 = fminf(fmaxf(c0[r], -9.f), 9.f); \
            float e0 = __expf(2.f * z0); \
            hn[m * HSTR + j0] = f2bf((e0 - 1.f) * __builtin_amdgcn_rcpf(e0 + 1.f)); \
            float z1 = fminf(fmaxf(c1[r], -9.f), 9.f); \
            float e1 = __expf(2.f * z1); \
            hn[m * HSTR + j1] = f2bf((e1 - 1.f) * __builtin_amdgcn_rcpf(e1 + 1.f)); \
        } \
        if (pre) { \
            _Pragma("unroll") \
            for (int e = 0; e < 4; ++e) { \
                int idx = tid * 4 + e; \
                int m = (int)((unsigned)idx / 57u); \
                int k = idx - m * 57; \
                x_lds[NB][m][k] = f2bf(xp[e]); \
            } \
        } \
        __syncthreads(); \
    } while (0)

    for (int t = 0; t < SEQ; t += 2) { STEP(0, 1, t); STEP(1, 0, t + 1); }
#undef STEP
#undef MFMA

    // ---- final h (buf0 after 1024 steps) -> hT output ----
    float* hT = out + (size_t)BATCH * OUT_F;
    #pragma unroll
    for (int r = 0; r < (MROWS * H_F) / 256; ++r) {
        int idx = tid + r * 256;
        int m = idx >> 7, k = idx & 127;
        hT[(size_t)(b0 + m) * H_F + k] = bf2f(h_lds[0][m][k]);
    }

    // ---- logits [16][18] ----
    for (int idx = tid; idx < MROWS * OUT_F; idx += 256) {
        int m = idx / OUT_F, o = idx - m * OUT_F;
        float acc = b_ho[o];
        for (int k = 0; k < H_F; ++k)
            acc = fmaf(bf2f(h_lds[0][m][k]), W_ho[o * H_F + k], acc);
        logits_lds[m][o] = acc;
    }
    __syncthreads();

    if (tid < MROWS) {
        float mx = -1e30f;
        #pragma unroll
        for (int o = 0; o < OUT_F; ++o) mx = fmaxf(mx, logits_lds[tid][o]);
        float s = 0.f;
        #pragma unroll
        for (int o = 0; o < OUT_F; ++o) s += expf(logits_lds[tid][o] - mx);
        red_lds[tid][0] = mx;
        red_lds[tid][1] = logf(s);
    }
    __syncthreads();

    for (int idx = tid; idx < MROWS * OUT_F; idx += 256) {
        int m = idx / OUT_F, o = idx - m * OUT_F;
        out[(size_t)(b0 + m) * OUT_F + o] =
            logits_lds[m][o] - red_lds[m][0] - red_lds[m][1];
    }
}

extern "C" void kernel_launch(void* const* d_in, const int* in_sizes, int n_in,
                              void* d_out, int out_size, void* d_ws, size_t ws_size,
                              hipStream_t stream) {
    const float* X    = (const float*)d_in[0];
    const float* W_ih = (const float*)d_in[1];
    const float* b_ih = (const float*)d_in[2];
    const float* W_hh = (const float*)d_in[3];
    const float* b_hh = (const float*)d_in[4];
    const float* W_ho = (const float*)d_in[5];
    const float* b_ho = (const float*)d_in[6];
    float* out = (float*)d_out;

    rnn_mfma_kernel<<<dim3(BATCH / MROWS), dim3(256), 0, stream>>>(
        X, W_ih, b_ih, W_hh, b_hh, W_ho, b_ho, out);
}

// Round 5
// 841.860 us; speedup vs baseline: 2.0510x; 1.0584x over previous
//
#include <hip/hip_runtime.h>
#include <math.h>

#define SEQ   1024
#define BATCH 1024
#define IN_F  57
#define H_F   128
#define OUT_F 18
#define MROWS 16     // batch rows per block
#define HSTR  136    // h_lds row stride in bf16 (272 B, 16B-aligned)
#define XSTR  72     // x_lds row stride in bf16 (144 B)

typedef __attribute__((ext_vector_type(8))) short bf8;     // MFMA A/B frag
typedef __attribute__((ext_vector_type(4))) float f32x4;   // MFMA C/D frag

static __device__ __forceinline__ short f2bf(float f) {    // fp32 -> bf16 RNE
    unsigned u = __builtin_bit_cast(unsigned, f);
    u = (u + 0x7FFFu + ((u >> 16) & 1u)) >> 16;
    return (short)u;
}
static __device__ __forceinline__ float bf2f(short s) {
    unsigned u = ((unsigned)(unsigned short)s) << 16;
    return __builtin_bit_cast(float, u);
}

// 64 blocks x 256 threads, block owns 16 batch rows for the whole sequence.
// Wave wv owns output cols [32wv, 32wv+32) as two 16x16x32 bf16 MFMA tiles.
// Per-step critical path is the whole ballgame (1 block/CU, all blocks run the
// same 1024 serial steps concurrently). R4 showed 1552 cyc/step; this round:
//  - X prefetch depth 2 (load at T, LDS-write at T+2) kills the HBM vmcnt stall
//  - 4 accumulators halve the dependent-MFMA chain (6 -> 3)
__global__ __launch_bounds__(256) void rnn_mfma_kernel(
    const float* __restrict__ X,     // [SEQ][BATCH][IN_F]
    const float* __restrict__ W_ih,  // [H_F][IN_F]
    const float* __restrict__ b_ih,  // [H_F]
    const float* __restrict__ W_hh,  // [H_F][H_F]
    const float* __restrict__ b_hh,  // [H_F]
    const float* __restrict__ W_ho,  // [OUT_F][H_F]
    const float* __restrict__ b_ho,  // [OUT_F]
    float* __restrict__ out)         // [BATCH][OUT_F] ++ [BATCH][H_F]
{
    const int tid  = threadIdx.x;
    const int lane = tid & 63;
    const int wv   = tid >> 6;
    const int n16  = lane & 15;
    const int quad = lane >> 4;
    const int b0   = blockIdx.x * MROWS;

    __shared__ short h_lds[2][MROWS][HSTR];
    __shared__ short x_lds[2][MROWS][XSTR];
    __shared__ float logits_lds[MROWS][OUT_F];
    __shared__ float red_lds[MROWS][2];

    const int j0 = wv * 32 + n16;
    const int j1 = j0 + 16;

    // ---- W_hh B-frags (bf16) in registers ----
    const float* wp0 = W_hh + j0 * H_F + quad * 8;
    const float* wp1 = W_hh + j1 * H_F + quad * 8;
#define LDW8(P) ({ \
        f32x4 p_ = *(const f32x4*)(P); \
        f32x4 q_ = *(const f32x4*)((P) + 4); \
        bf8 f_; \
        f_[0]=f2bf(p_[0]); f_[1]=f2bf(p_[1]); f_[2]=f2bf(p_[2]); f_[3]=f2bf(p_[3]); \
        f_[4]=f2bf(q_[0]); f_[5]=f2bf(q_[1]); f_[6]=f2bf(q_[2]); f_[7]=f2bf(q_[3]); \
        f_; })
    bf8 wh00 = LDW8(wp0 +  0), wh01 = LDW8(wp0 + 32), wh02 = LDW8(wp0 + 64), wh03 = LDW8(wp0 + 96);
    bf8 wh10 = LDW8(wp1 +  0), wh11 = LDW8(wp1 + 32), wh12 = LDW8(wp1 + 64), wh13 = LDW8(wp1 + 96);

    // ---- W_ih B-frags (K 57->64 zero-pad) ----
#define LDWI(J, KS) ({ \
        bf8 f_; \
        _Pragma("unroll") \
        for (int i_ = 0; i_ < 8; ++i_) { \
            int k_ = (KS) * 32 + quad * 8 + i_; \
            f_[i_] = (k_ < IN_F) ? f2bf(W_ih[(J) * IN_F + k_]) : (short)0; \
        } f_; })
    bf8 wi00 = LDWI(j0, 0), wi01 = LDWI(j0, 1), wi10 = LDWI(j1, 0), wi11 = LDWI(j1, 1);

    const float bias0 = b_ih[j0] + b_hh[j0];
    const float bias1 = b_ih[j1] + b_hh[j1];

    // ---- x staging constants: 912 floats/step = 228 f32x4 lanes ----
    const bool  xlane = (tid < 228);
    const size_t tstride = (size_t)BATCH * IN_F;
    const float* xbase = X + (size_t)b0 * IN_F + tid * 4;
    // per-element LDS targets for this lane's 4 floats
    int xm[4], xk[4];
    #pragma unroll
    for (int e = 0; e < 4; ++e) {
        int idx = tid * 4 + e;
        xm[e] = (int)((unsigned)idx / 57u);
        xk[e] = idx - xm[e] * 57;
    }

    // ---- init: h0 = 0, zero x pads, stage x_0 directly, prefetch x_1, x_2 ----
    for (int i = tid; i < MROWS * HSTR; i += 256) (&h_lds[0][0][0])[i] = 0;
    for (int i = tid; i < 2 * MROWS * XSTR; i += 256) (&x_lds[0][0][0])[i] = 0;
    f32x4 xq0 = {0,0,0,0}, xq1 = {0,0,0,0};
    if (xlane) {
        f32x4 v = *(const f32x4*)(xbase);
        #pragma unroll
        for (int e = 0; e < 4; ++e) x_lds[0][xm[e]][xk[e]] = f2bf(v[e]);
        xq1 = *(const f32x4*)(xbase + 1 * tstride);   // x_1  (written at T=0)
        xq0 = *(const f32x4*)(xbase + 2 * tstride);   // x_2  (written at T=1)
    }
    __syncthreads();

#define MFMA __builtin_amdgcn_mfma_f32_16x16x32_bf16
#define STEP(CB, NB, T, XS) do { \
        /* A-frags for this step */ \
        const short* hc = &h_lds[CB][0][0] + n16 * HSTR + quad * 8; \
        const short* xc = &x_lds[CB][0][0] + n16 * XSTR + quad * 8; \
        bf8 ah0 = *(const bf8*)(hc +  0); \
        bf8 ah1 = *(const bf8*)(hc + 32); \
        bf8 ah2 = *(const bf8*)(hc + 64); \
        bf8 ah3 = *(const bf8*)(hc + 96); \
        bf8 ax0 = *(const bf8*)(xc +  0); \
        bf8 ax1 = *(const bf8*)(xc + 32); \
        /* stage x_{T+1} (loaded 2 steps ago -> no vmcnt stall) into NB now */ \
        if (((T) + 1 < SEQ) && xlane) { \
            _Pragma("unroll") \
            for (int e = 0; e < 4; ++e) x_lds[NB][xm[e]][xk[e]] = f2bf(XS[e]); \
        } \
        /* issue load of x_{T+3} into the same parity slot */ \
        if (((T) + 3 < SEQ) && xlane) \
            XS = *(const f32x4*)(xbase + (size_t)((T) + 3) * tstride); \
        /* 12 MFMAs, 4 chains of depth 3 */ \
        f32x4 c0a = {bias0, bias0, bias0, bias0}, c0b = {0.f, 0.f, 0.f, 0.f}; \
        f32x4 c1a = {bias1, bias1, bias1, bias1}, c1b = {0.f, 0.f, 0.f, 0.f}; \
        c0a = MFMA(ah0, wh00, c0a, 0, 0, 0); \
        c1a = MFMA(ah0, wh10, c1a, 0, 0, 0); \
        c0b = MFMA(ah1, wh01, c0b, 0, 0, 0); \
        c1b = MFMA(ah1, wh11, c1b, 0, 0, 0); \
        c0a = MFMA(ah2, wh02, c0a, 0, 0, 0); \
        c1a = MFMA(ah2, wh12, c1a, 0, 0, 0); \
        c0b = MFMA(ah3, wh03, c0b, 0, 0, 0); \
        c1b = MFMA(ah3, wh13, c1b, 0, 0, 0); \
        c0a = MFMA(ax0, wi00, c0a, 0, 0, 0); \
        c1a = MFMA(ax0, wi10, c1a, 0, 0, 0); \
        c0b = MFMA(ax1, wi01, c0b, 0, 0, 0); \
        c1b = MFMA(ax1, wi11, c1b, 0, 0, 0); \
        short* hn = &h_lds[NB][0][0]; \
        _Pragma("unroll") \
        for (int r = 0; r < 4; ++r) { \
            int m = quad * 4 + r; \
            float z0 = fminf(fmaxf(c0a[r] + c0b[r], -9.f), 9.f); \
            float e0 = __expf(2.f * z0); \
            hn[m * HSTR + j0] = f2bf((e0 - 1.f) * __builtin_amdgcn_rcpf(e0 + 1.f)); \
            float z1 = fminf(fmaxf(c1a[r] + c1b[r], -9.f), 9.f); \
            float e1 = __expf(2.f * z1); \
            hn[m * HSTR + j1] = f2bf((e1 - 1.f) * __builtin_amdgcn_rcpf(e1 + 1.f)); \
        } \
        __syncthreads(); \
    } while (0)

    for (int t = 0; t < SEQ; t += 2) {
        STEP(0, 1, t,     xq1);
        STEP(1, 0, t + 1, xq0);
    }
#undef STEP
#undef MFMA

    // ---- final h (buf0) -> hT ----
    float* hT = out + (size_t)BATCH * OUT_F;
    #pragma unroll
    for (int r = 0; r < (MROWS * H_F) / 256; ++r) {
        int idx = tid + r * 256;
        int m = idx >> 7, k = idx & 127;
        hT[(size_t)(b0 + m) * H_F + k] = bf2f(h_lds[0][m][k]);
    }

    // ---- logits [16][18] ----
    for (int idx = tid; idx < MROWS * OUT_F; idx += 256) {
        int m = idx / OUT_F, o = idx - m * OUT_F;
        float acc = b_ho[o];
        for (int k = 0; k < H_F; ++k)
            acc = fmaf(bf2f(h_lds[0][m][k]), W_ho[o * H_F + k], acc);
        logits_lds[m][o] = acc;
    }
    __syncthreads();

    if (tid < MROWS) {
        float mx = -1e30f;
        #pragma unroll
        for (int o = 0; o < OUT_F; ++o) mx = fmaxf(mx, logits_lds[tid][o]);
        float s = 0.f;
        #pragma unroll
        for (int o = 0; o < OUT_F; ++o) s += expf(logits_lds[tid][o] - mx);
        red_lds[tid][0] = mx;
        red_lds[tid][1] = logf(s);
    }
    __syncthreads();

    for (int idx = tid; idx < MROWS * OUT_F; idx += 256) {
        int m = idx / OUT_F, o = idx - m * OUT_F;
        out[(size_t)(b0 + m) * OUT_F + o] =
            logits_lds[m][o] - red_lds[m][0] - red_lds[m][1];
    }
}

extern "C" void kernel_launch(void* const* d_in, const int* in_sizes, int n_in,
                              void* d_out, int out_size, void* d_ws, size_t ws_size,
                              hipStream_t stream) {
    const float* X    = (const float*)d_in[0];
    const float* W_ih = (const float*)d_in[1];
    const float* b_ih = (const float*)d_in[2];
    const float* W_hh = (const float*)d_in[3];
    const float* b_hh = (const float*)d_in[4];
    const float* W_ho = (const float*)d_in[5];
    const float* b_ho = (const float*)d_in[6];
    float* out = (float*)d_out;

    rnn_mfma_kernel<<<dim3(BATCH / MROWS), dim3(256), 0, stream>>>(
        X, W_ih, b_ih, W_hh, b_hh, W_ho, b_ho, out);
}